// Round 2
// baseline (1045.077 us; speedup 1.0000x reference)
//
#include <hip/hip_runtime.h>

typedef unsigned short ushort_t;
typedef __bf16 bf16x8 __attribute__((ext_vector_type(8)));
typedef float f32x4 __attribute__((ext_vector_type(4)));

__device__ __forceinline__ ushort_t f2bf(float f) {
    unsigned u;
    __builtin_memcpy(&u, &f, 4);
    u += 0x7fffu + ((u >> 16) & 1u);   // RNE
    return (ushort_t)(u >> 16);
}

__device__ __forceinline__ float silu(float x) {
    // x * sigmoid(x) = x / (1 + exp(-x)); exp via native exp2
    float e = __builtin_amdgcn_exp2f(x * -1.442695040888963f);
    return x * __builtin_amdgcn_rcpf(1.0f + e);
}

// Fragment-swizzled LDS layout for 16x16x32 bf16 MFMA operands:
// element (row, k) -> frag = (row>>4)*4 + (k>>5)          [1 KB per frag]
//                     slot = (row&15) + 16*((k>>3)&3)      [16 B per slot]
//                     byte = (k&7)*2
// Reads: lane reads its own frag at slot==lane -> ds_read_b128, conflict-free.

__global__ __launch_bounds__(256, 2) void mlp_kernel(
    const float* __restrict__ v,    // [N,3] f32
    const float* __restrict__ rij,  // [E,3] f32
    const float* __restrict__ W0,   // [128,4] f32
    const float* __restrict__ b0,   // [128]
    const float* __restrict__ W1,   // [128,128] (n,k)
    const float* __restrict__ b1,   // [128]
    const float* __restrict__ W2,   // [128]
    const float* __restrict__ b2,   // [1]
    const int* __restrict__ eidx,   // [2,E] int32
    float* __restrict__ sum_i, float* __restrict__ sum_j,
    unsigned* __restrict__ cnt_i, unsigned* __restrict__ cnt_j,
    int E, int nchunks)
{
    __shared__ ushort_t sW1[16384];   // 32 KB, frag-swizzled bf16
    __shared__ ushort_t sH0[16384];   // 32 KB, frag-swizzled bf16; wave w owns frags [8w, 8w+8)

    const int tid  = threadIdx.x;
    const int lane = tid & 63;
    const int wave = tid >> 6;

    // ---- stage W1 (f32 -> bf16) into swizzled LDS (once per block) ----
    {
        int n = tid >> 1, half = tid & 1;
        const float* src = W1 + n * 128;
#pragma unroll
        for (int dk = 0; dk < 8; dk++) {
            int k0   = half * 64 + dk * 8;
            int frag = (n >> 4) * 4 + (k0 >> 5);
            int slot = (n & 15) + 16 * ((k0 >> 3) & 3);
            ushort_t tmp[8];
#pragma unroll
            for (int t = 0; t < 8; t++) tmp[t] = f2bf(src[k0 + t]);
            *(uint4*)(&sW1[frag * 512 + slot * 8]) = *(const uint4*)tmp;
        }
    }

    // ---- per-lane constant registers ----
    float4 w0q[2]; float b0v[2];
#pragma unroll
    for (int kk = 0; kk < 2; kk++) {
        int h = 2 * lane + kk;
        w0q[kk].x = W0[h * 4 + 0];
        w0q[kk].y = W0[h * 4 + 1];
        w0q[kk].z = W0[h * 4 + 2];
        w0q[kk].w = W0[h * 4 + 3];
        b0v[kk]   = b0[h];
    }
    float b1v[8], w2v[8];
#pragma unroll
    for (int nt = 0; nt < 8; nt++) {
        int ccol = nt * 16 + (lane & 15);
        b1v[nt] = b1[ccol];
        w2v[nt] = W2[ccol];
    }
    const float b2f = b2[0];

    __syncthreads();   // sW1 ready; after this the hot loop is barrier-free

    const int q = lane >> 4, c = lane & 15;
    // phase-A write address pieces (lane covers k = 2*lane, 2*lane+1)
    const int wr_fragk = lane >> 4;            // k>>5
    const int wr_slot16 = 16 * ((lane >> 2) & 3);
    const int wr_b = lane & 3;                 // uint offset within slot

    for (int chunk = blockIdx.x; chunk < nchunks; chunk += gridDim.x) {
        // ================= phase A: layer0 -> swizzled bf16 H0 =================
        const int ebase = chunk * 64 + wave * 16;
#pragma unroll 1
        for (int le = 0; le < 16; le++) {
            int e = ebase + le;
            bool valid = (e < E);
            float rr = 0.f, vx = 0.f, vy = 0.f, vz = 0.f;
            if (valid) {
                int i = eidx[e], j = eidx[E + e];
                float r0 = rij[3 * e];
                float r1 = rij[3 * e + 1];
                float r2 = rij[3 * e + 2];
                rr = sqrtf(fmaf(r0, r0, fmaf(r1, r1, r2 * r2))) * (1.0f / 3.0f); // /H
                vx = v[3 * i]     - v[3 * j];
                vy = v[3 * i + 1] - v[3 * j + 1];
                vz = v[3 * i + 2] - v[3 * j + 2];
                if (lane == 0) atomicAdd(&cnt_i[i], 1u);
                if (lane == 1) atomicAdd(&cnt_j[j], 1u);
            }
            float si[2], sj[2];
#pragma unroll
            for (int kk = 0; kk < 2; kk++) {
                float cc = fmaf(w0q[kk].x, rr, b0v[kk]);
                float dd = fmaf(w0q[kk].y, vx, fmaf(w0q[kk].z, vy, w0q[kk].w * vz));
                si[kk] = valid ? silu(cc + dd) : 0.f;
                sj[kk] = valid ? silu(cc - dd) : 0.f;
            }
            unsigned pi = (unsigned)f2bf(si[0]) | ((unsigned)f2bf(si[1]) << 16);
            unsigned pj = (unsigned)f2bf(sj[0]) | ((unsigned)f2bf(sj[1]) << 16);
            int mi = wave * 32 + 2 * le;          // row for x_i; mi+1 for x_j
            int fi = (((mi) >> 4) * 4 + wr_fragk) * 256 + (((mi) & 15) + wr_slot16) * 4 + wr_b;
            int fj = (((mi + 1) >> 4) * 4 + wr_fragk) * 256 + (((mi + 1) & 15) + wr_slot16) * 4 + wr_b;
            ((unsigned*)sH0)[fi] = pi;
            ((unsigned*)sH0)[fj] = pj;
        }

        // ================= GEMM: h1_pre = H0 @ W1^T (wave-local rows) =================
        f32x4 acc[2][8];
#pragma unroll
        for (int t = 0; t < 2; t++)
#pragma unroll
            for (int nt = 0; nt < 8; nt++)
                acc[t][nt] = (f32x4){0.f, 0.f, 0.f, 0.f};

#pragma unroll
        for (int ks = 0; ks < 4; ks++) {
            bf16x8 a0 = *(const bf16x8*)(&sH0[((2 * wave + 0) * 4 + ks) * 512 + lane * 8]);
            bf16x8 a1 = *(const bf16x8*)(&sH0[((2 * wave + 1) * 4 + ks) * 512 + lane * 8]);
#pragma unroll
            for (int nt = 0; nt < 8; nt++) {
                bf16x8 bb = *(const bf16x8*)(&sW1[(nt * 4 + ks) * 512 + lane * 8]);
                acc[0][nt] = __builtin_amdgcn_mfma_f32_16x16x32_bf16(a0, bb, acc[0][nt], 0, 0, 0);
                acc[1][nt] = __builtin_amdgcn_mfma_f32_16x16x32_bf16(a1, bb, acc[1][nt], 0, 0, 0);
            }
        }

        // ================= epilogue: silu(h1)+b1 -> dot W2 -> +b2 -> scatter =================
        float rs[2][4] = {{0.f, 0.f, 0.f, 0.f}, {0.f, 0.f, 0.f, 0.f}};
#pragma unroll
        for (int t = 0; t < 2; t++)
#pragma unroll
            for (int nt = 0; nt < 8; nt++)
#pragma unroll
                for (int r = 0; r < 4; r++) {
                    float x = acc[t][nt][r] + b1v[nt];
                    rs[t][r] = fmaf(silu(x), w2v[nt], rs[t][r]);
                }
#pragma unroll
        for (int t = 0; t < 2; t++)
#pragma unroll
            for (int r = 0; r < 4; r++) {
                float s = rs[t][r];
                s += __shfl_xor(s, 1, 64);
                s += __shfl_xor(s, 2, 64);
                s += __shfl_xor(s, 4, 64);
                s += __shfl_xor(s, 8, 64);
                if (c == 0) {
                    int row = wave * 32 + t * 16 + q * 4 + r;
                    int el = row >> 1;
                    int e = chunk * 64 + el;
                    if (e < E) {
                        if (row & 1) atomicAdd(&sum_j[eidx[E + e]], s + b2f);
                        else         atomicAdd(&sum_i[eidx[e]],     s + b2f);
                    }
                }
            }
        // wave-local LDS WAR across iterations is safe: DS ops of one wave are in-order.
    }
}

__global__ void finalize_kernel(const float* __restrict__ sum_i, const float* __restrict__ sum_j,
                                const unsigned* __restrict__ cnt_i, const unsigned* __restrict__ cnt_j,
                                float* __restrict__ out, int N)
{
    int n = blockIdx.x * 256 + threadIdx.x;
    if (n < N) {
        float a = sum_i[n] / fmaxf((float)cnt_i[n], 1.0f);
        float bsum = sum_j[n] / fmaxf((float)cnt_j[n], 1.0f);
        out[n] = a + bsum;
    }
}

extern "C" void kernel_launch(void* const* d_in, const int* in_sizes, int n_in,
                              void* d_out, int out_size, void* d_ws, size_t ws_size,
                              hipStream_t stream) {
    const float* v   = (const float*)d_in[0];
    const float* rij = (const float*)d_in[1];
    const float* W0  = (const float*)d_in[2];
    const float* b0  = (const float*)d_in[3];
    const float* W1  = (const float*)d_in[4];
    const float* b1  = (const float*)d_in[5];
    const float* W2  = (const float*)d_in[6];
    const float* b2  = (const float*)d_in[7];
    const int* eidx  = (const int*)d_in[8];

    const int E = in_sizes[1] / 3;
    const int N = out_size;

    float* sum_i = (float*)d_ws;
    float* sum_j = sum_i + N;
    unsigned* cnt_i = (unsigned*)(sum_j + N);
    unsigned* cnt_j = cnt_i + N;

    hipMemsetAsync(d_ws, 0, (size_t)4 * N * sizeof(float), stream);

    int nchunks = (E + 63) / 64;
    int grid = nchunks < 512 ? nchunks : 512;
    mlp_kernel<<<grid, 256, 0, stream>>>(v, rij, W0, b0, W1, b1, W2, b2, eidx,
                                         sum_i, sum_j, cnt_i, cnt_j, E, nchunks);
    finalize_kernel<<<(N + 255) / 256, 256, 0, stream>>>(sum_i, sum_j, cnt_i, cnt_j,
                                                         (float*)d_out, N);
}

// Round 3
// 438.745 us; speedup vs baseline: 2.3820x; 2.3820x over previous
//
#include <hip/hip_runtime.h>

typedef unsigned short ushort_t;
typedef __bf16 bf16x8 __attribute__((ext_vector_type(8)));
typedef __bf16 bf16x2 __attribute__((ext_vector_type(2)));
typedef float f32x4 __attribute__((ext_vector_type(4)));

__device__ __forceinline__ ushort_t f2bf(float f) {
    unsigned u;
    __builtin_memcpy(&u, &f, 4);
    u += 0x7fffu + ((u >> 16) & 1u);   // RNE
    return (ushort_t)(u >> 16);
}

__device__ __forceinline__ float silu(float x) {
    float e = __builtin_amdgcn_exp2f(x * -1.442695040888963f);
    return x * __builtin_amdgcn_rcpf(1.0f + e);
}

__device__ __forceinline__ float rdlane(float v, int l) {
    return __builtin_bit_cast(float, __builtin_amdgcn_readlane(__builtin_bit_cast(int, v), l));
}

// XOR-swizzled A-fragment LDS layout for 16x16x32 bf16 MFMA:
// element (row,k) -> frag  = (row>>4)*4 + (k>>5)                         [1 KB]
//                    slot  = ((row&15) ^ ((k>>5)&3) ^ (((k>>3)&3)<<2))
//                            + 16*((k>>3)&3)                             [16 B]
//                    byte  = (k&7)*2
// Reads (lane m=l&15,q=l>>4): b128 at slot ((m^ks^(q<<2))&15)+16q -> 64 distinct
// slots, conflict-free. Writes (k=2*lane): banks spread over all 32 -> 2-way (free).

__global__ __launch_bounds__(256, 2) void mlp_kernel(
    const float* __restrict__ v,    // [N,3] f32
    const float* __restrict__ rij,  // [E,3] f32
    const float* __restrict__ W0,   // [128,4]
    const float* __restrict__ b0,   // [128]
    const float* __restrict__ W1,   // [128,128] (n,k)
    const float* __restrict__ b1,   // [128]
    const float* __restrict__ W2,   // [128]
    const float* __restrict__ b2,   // [1]
    const int* __restrict__ eidx,   // [2,E] int32
    float* __restrict__ sum_i, float* __restrict__ sum_j,
    unsigned* __restrict__ cnt_i, unsigned* __restrict__ cnt_j,
    int E, int nchunks)
{
    __shared__ ushort_t sW1[16384];   // 32 KB, frag layout (unswizzled)
    __shared__ ushort_t sH0[16384];   // 32 KB, XOR-swizzled; wave w owns frags [8w,8w+8)

    const int tid  = threadIdx.x;
    const int lane = tid & 63;
    const int wave = tid >> 6;

    // ---- stage W1 (f32 -> bf16) into LDS (once per block) ----
    {
        int n = tid >> 1, half = tid & 1;
        const float* src = W1 + n * 128;
#pragma unroll
        for (int dk = 0; dk < 8; dk++) {
            int k0   = half * 64 + dk * 8;
            int frag = (n >> 4) * 4 + (k0 >> 5);
            int slot = (n & 15) + 16 * ((k0 >> 3) & 3);
            ushort_t tmp[8];
#pragma unroll
            for (int t = 0; t < 8; t++) tmp[t] = f2bf(src[k0 + t]);
            *(uint4*)(&sW1[frag * 512 + slot * 8]) = *(const uint4*)tmp;
        }
    }

    // ---- per-lane constants ----
    float4 w0q[2]; float b0v[2];
#pragma unroll
    for (int kk = 0; kk < 2; kk++) {
        int h = 2 * lane + kk;
        w0q[kk].x = W0[h * 4 + 0];
        w0q[kk].y = W0[h * 4 + 1];
        w0q[kk].z = W0[h * 4 + 2];
        w0q[kk].w = W0[h * 4 + 3];
        b0v[kk]   = b0[h];
    }
    float b1v[8], w2v[8];
#pragma unroll
    for (int nt = 0; nt < 8; nt++) {
        int ccol = nt * 16 + (lane & 15);
        b1v[nt] = b1[ccol];
        w2v[nt] = W2[ccol];
    }
    const float b2f = b2[0];

    __syncthreads();   // sW1 ready; hot loop below is barrier-free

    const int q = lane >> 4, c = lane & 15, p = (lane >> 2) & 3, bsub = lane & 3;

    for (int chunk = blockIdx.x; chunk < nchunks; chunk += gridDim.x) {
        const int ebase = chunk * 64 + wave * 16;

        // ===== parallel preload: lane l -> (edge l>>2, component l&3) =====
        const int ple  = lane >> 2;
        const int comp = lane & 3;
        const int pe   = ebase + ple;
        float val = 0.f;
        int idx_reg = 0;
        if (pe < E) {
            if (comp == 3) {
                float r0 = rij[3 * pe], r1 = rij[3 * pe + 1], r2 = rij[3 * pe + 2];
                val = sqrtf(fmaf(r0, r0, fmaf(r1, r1, r2 * r2))) * (1.0f / 3.0f);
            } else {
                int i = eidx[pe], j = eidx[E + pe];
                idx_reg = (comp == 1) ? j : i;
                val = v[3 * i + comp] - v[3 * j + comp];
                if (comp == 0) atomicAdd(&cnt_i[i], 1u);
                if (comp == 1) atomicAdd(&cnt_j[j], 1u);
            }
        }

        // ===== phase A: layer0 -> swizzled bf16 H0 (lane covers h=2l,2l+1) =====
#pragma unroll
        for (int le = 0; le < 16; le++) {
            float vx = rdlane(val, le * 4 + 0);
            float vy = rdlane(val, le * 4 + 1);
            float vz = rdlane(val, le * 4 + 2);
            float rr = rdlane(val, le * 4 + 3);
            float si[2], sj[2];
#pragma unroll
            for (int kk = 0; kk < 2; kk++) {
                float cc = fmaf(w0q[kk].x, rr, b0v[kk]);
                float dd = fmaf(w0q[kk].y, vx, fmaf(w0q[kk].z, vy, w0q[kk].w * vz));
                si[kk] = silu(cc + dd);
                sj[kk] = silu(cc - dd);
            }
            bf16x2 pki, pkj;
            pki[0] = (__bf16)si[0]; pki[1] = (__bf16)si[1];
            pkj[0] = (__bf16)sj[0]; pkj[1] = (__bf16)sj[1];
            int mi = wave * 32 + 2 * le;          // x_i row; x_j row = mi+1
            int fr_i = ((mi >> 4) << 2) + q;
            int fr_j = (((mi + 1) >> 4) << 2) + q;
            int sl_i = (((mi & 15) ^ q ^ (p << 2)) & 15) + (p << 4);
            int sl_j = ((((mi + 1) & 15) ^ q ^ (p << 2)) & 15) + (p << 4);
            ((unsigned*)sH0)[fr_i * 256 + sl_i * 4 + bsub] = __builtin_bit_cast(unsigned, pki);
            ((unsigned*)sH0)[fr_j * 256 + sl_j * 4 + bsub] = __builtin_bit_cast(unsigned, pkj);
        }

        // ===== GEMM: h1_pre = H0 @ W1^T (wave-local rows, no barrier) =====
        f32x4 acc[2][8];
#pragma unroll
        for (int t = 0; t < 2; t++)
#pragma unroll
            for (int nt = 0; nt < 8; nt++)
                acc[t][nt] = (f32x4){0.f, 0.f, 0.f, 0.f};

#pragma unroll
        for (int ks = 0; ks < 4; ks++) {
            int sl_rd = (((lane & 15) ^ ks ^ (q << 2)) & 15) + 16 * q;
            bf16x8 a0 = *(const bf16x8*)(&sH0[((2 * wave + 0) * 4 + ks) * 512 + sl_rd * 8]);
            bf16x8 a1 = *(const bf16x8*)(&sH0[((2 * wave + 1) * 4 + ks) * 512 + sl_rd * 8]);
#pragma unroll
            for (int nt = 0; nt < 8; nt++) {
                bf16x8 bb = *(const bf16x8*)(&sW1[(nt * 4 + ks) * 512 + lane * 8]);
                acc[0][nt] = __builtin_amdgcn_mfma_f32_16x16x32_bf16(a0, bb, acc[0][nt], 0, 0, 0);
                acc[1][nt] = __builtin_amdgcn_mfma_f32_16x16x32_bf16(a1, bb, acc[1][nt], 0, 0, 0);
            }
        }

        // ===== epilogue: silu(h1+b1) . W2 -> +b2 -> scatter-add =====
        float rs[2][4] = {{0.f, 0.f, 0.f, 0.f}, {0.f, 0.f, 0.f, 0.f}};
#pragma unroll
        for (int t = 0; t < 2; t++)
#pragma unroll
            for (int nt = 0; nt < 8; nt++)
#pragma unroll
                for (int r = 0; r < 4; r++) {
                    float x = acc[t][nt][r] + b1v[nt];
                    rs[t][r] = fmaf(silu(x), w2v[nt], rs[t][r]);
                }
#pragma unroll
        for (int t = 0; t < 2; t++)
#pragma unroll
            for (int r = 0; r < 4; r++) {
                float s = rs[t][r];
                s += __shfl_xor(s, 1, 64);
                s += __shfl_xor(s, 2, 64);
                s += __shfl_xor(s, 4, 64);
                s += __shfl_xor(s, 8, 64);
                int el  = t * 8 + q * 2 + (r >> 1);        // edge within wave's 16
                int src = el * 4 + (r & 1);                // comp0 holds i, comp1 holds j
                int node = __shfl(idx_reg, src, 64);
                int e = ebase + el;
                if (c == 0 && e < E) {
                    if (r & 1) atomicAdd(&sum_j[node], s + b2f);
                    else       atomicAdd(&sum_i[node], s + b2f);
                }
            }
        // wave-local LDS WAR across chunks is safe: one wave's DS ops are in-order.
    }
}

__global__ void finalize_kernel(const float* __restrict__ sum_i, const float* __restrict__ sum_j,
                                const unsigned* __restrict__ cnt_i, const unsigned* __restrict__ cnt_j,
                                float* __restrict__ out, int N)
{
    int n = blockIdx.x * 256 + threadIdx.x;
    if (n < N) {
        float a = sum_i[n] / fmaxf((float)cnt_i[n], 1.0f);
        float bsum = sum_j[n] / fmaxf((float)cnt_j[n], 1.0f);
        out[n] = a + bsum;
    }
}

extern "C" void kernel_launch(void* const* d_in, const int* in_sizes, int n_in,
                              void* d_out, int out_size, void* d_ws, size_t ws_size,
                              hipStream_t stream) {
    const float* v   = (const float*)d_in[0];
    const float* rij = (const float*)d_in[1];
    const float* W0  = (const float*)d_in[2];
    const float* b0  = (const float*)d_in[3];
    const float* W1  = (const float*)d_in[4];
    const float* b1  = (const float*)d_in[5];
    const float* W2  = (const float*)d_in[6];
    const float* b2  = (const float*)d_in[7];
    const int* eidx  = (const int*)d_in[8];

    const int E = in_sizes[1] / 3;
    const int N = out_size;

    float* sum_i = (float*)d_ws;
    float* sum_j = sum_i + N;
    unsigned* cnt_i = (unsigned*)(sum_j + N);
    unsigned* cnt_j = cnt_i + N;

    hipMemsetAsync(d_ws, 0, (size_t)4 * N * sizeof(float), stream);

    int nchunks = (E + 63) / 64;
    int grid = nchunks < 512 ? nchunks : 512;
    mlp_kernel<<<grid, 256, 0, stream>>>(v, rij, W0, b0, W1, b1, W2, b2, eidx,
                                         sum_i, sum_j, cnt_i, cnt_j, E, nchunks);
    finalize_kernel<<<(N + 255) / 256, 256, 0, stream>>>(sum_i, sum_j, cnt_i, cnt_j,
                                                         (float*)d_out, N);
}

// Round 4
// 424.808 us; speedup vs baseline: 2.4601x; 1.0328x over previous
//
#include <hip/hip_runtime.h>

typedef unsigned short ushort_t;
typedef __bf16 bf16x8 __attribute__((ext_vector_type(8)));
typedef __bf16 bf16x2 __attribute__((ext_vector_type(2)));
typedef float f32x4 __attribute__((ext_vector_type(4)));

__device__ __forceinline__ ushort_t f2bf(float f) {
    unsigned u;
    __builtin_memcpy(&u, &f, 4);
    u += 0x7fffu + ((u >> 16) & 1u);   // RNE
    return (ushort_t)(u >> 16);
}

__device__ __forceinline__ float silu(float x) {
    float e = __builtin_amdgcn_exp2f(x * -1.442695040888963f);
    return x * __builtin_amdgcn_rcpf(1.0f + e);
}

__device__ __forceinline__ float rdlane(float v, int l) {
    return __builtin_bit_cast(float, __builtin_amdgcn_readlane(__builtin_bit_cast(int, v), l));
}

// XOR-swizzled A-fragment LDS layout for 16x16x32 bf16 MFMA (verified R3):
// element (row,k) -> frag  = (row>>4)*4 + (k>>5)                         [1 KB]
//                    slot  = ((row&15) ^ ((k>>5)&3) ^ (((k>>3)&3)<<2))
//                            + 16*((k>>3)&3)                             [16 B]
//                    byte  = (k&7)*2
// Reads: b128, 64 distinct slots, conflict-free. Writes: 2-way (free).

// Packed scatter accumulator: one f64 atomic carries sum + 65536*count.
// |s| <~ 10, count <~ 100 -> 65536*cnt < 2^23; double holds both exactly.
#define CNT_UNIT 65536.0

__global__ __launch_bounds__(256, 2) void mlp_kernel(
    const float* __restrict__ v,    // [N,3] f32
    const float* __restrict__ rij,  // [E,3] f32
    const float* __restrict__ W0,   // [128,4]
    const float* __restrict__ b0,   // [128]
    const float* __restrict__ W1,   // [128,128] (n,k)
    const float* __restrict__ b1,   // [128]
    const float* __restrict__ W2,   // [128]
    const float* __restrict__ b2,   // [1]
    const int* __restrict__ eidx,   // [2,E] int32
    double* __restrict__ acc_i, double* __restrict__ acc_j,
    int E, int nchunks)
{
    __shared__ ushort_t sW1[16384];   // 32 KB, frag layout (unswizzled)
    __shared__ ushort_t sH0[16384];   // 32 KB, XOR-swizzled; wave w owns frags [8w,8w+8)

    const int tid  = threadIdx.x;
    const int lane = tid & 63;
    const int wave = tid >> 6;

    // ---- stage W1 (f32 -> bf16) into LDS (once per block) ----
    {
        int n = tid >> 1, half = tid & 1;
        const float* src = W1 + n * 128;
#pragma unroll
        for (int dk = 0; dk < 8; dk++) {
            int k0   = half * 64 + dk * 8;
            int frag = (n >> 4) * 4 + (k0 >> 5);
            int slot = (n & 15) + 16 * ((k0 >> 3) & 3);
            ushort_t tmp[8];
#pragma unroll
            for (int t = 0; t < 8; t++) tmp[t] = f2bf(src[k0 + t]);
            *(uint4*)(&sW1[frag * 512 + slot * 8]) = *(const uint4*)tmp;
        }
    }

    // ---- per-lane constants ----
    float4 w0q[2]; float b0v[2];
#pragma unroll
    for (int kk = 0; kk < 2; kk++) {
        int h = 2 * lane + kk;
        w0q[kk].x = W0[h * 4 + 0];
        w0q[kk].y = W0[h * 4 + 1];
        w0q[kk].z = W0[h * 4 + 2];
        w0q[kk].w = W0[h * 4 + 3];
        b0v[kk]   = b0[h];
    }
    float b1v[8], w2v[8];
#pragma unroll
    for (int nt = 0; nt < 8; nt++) {
        int ccol = nt * 16 + (lane & 15);
        b1v[nt] = b1[ccol];
        w2v[nt] = W2[ccol];
    }
    const float b2f = b2[0];

    __syncthreads();   // sW1 ready; hot loop below is barrier-free

    const int q = lane >> 4, c = lane & 15, p = (lane >> 2) & 3, bsub = lane & 3;
    const int ple  = lane >> 2;     // edge-in-wave this lane preloads
    const int comp = lane & 3;      // 0..2: v component, 3: |r|/H

    // ---- gather preload for one chunk (lane-parallel) ----
    auto preload = [&](int ch, float& val_o, int& idx_o) {
        float val = 0.f; int idxr = 0;
        int pe = ch * 64 + wave * 16 + ple;
        if (ch < nchunks && pe < E) {
            if (comp == 3) {
                float r0 = rij[3 * pe], r1 = rij[3 * pe + 1], r2 = rij[3 * pe + 2];
                val = sqrtf(fmaf(r0, r0, fmaf(r1, r1, r2 * r2))) * (1.0f / 3.0f);
            } else {
                int i = eidx[pe], jj = eidx[E + pe];
                idxr = (comp == 1) ? jj : i;
                val = v[3 * i + comp] - v[3 * jj + comp];
            }
        }
        val_o = val; idx_o = idxr;
    };

    float val; int idxr;
    preload(blockIdx.x, val, idxr);   // prologue load for first chunk

    for (int chunk = blockIdx.x; chunk < nchunks; chunk += gridDim.x) {
        const float val_cur = val;
        const int   idx_cur = idxr;
        // issue next chunk's gathers now; consumed one full iteration later
        preload(chunk + (int)gridDim.x, val, idxr);

        const int ebase = chunk * 64 + wave * 16;

        // ===== phase A: layer0 -> swizzled bf16 H0 (lane covers h=2l,2l+1) =====
#pragma unroll
        for (int le = 0; le < 16; le++) {
            float vx = rdlane(val_cur, le * 4 + 0);
            float vy = rdlane(val_cur, le * 4 + 1);
            float vz = rdlane(val_cur, le * 4 + 2);
            float rr = rdlane(val_cur, le * 4 + 3);
            float si[2], sj[2];
#pragma unroll
            for (int kk = 0; kk < 2; kk++) {
                float cc = fmaf(w0q[kk].x, rr, b0v[kk]);
                float dd = fmaf(w0q[kk].y, vx, fmaf(w0q[kk].z, vy, w0q[kk].w * vz));
                si[kk] = silu(cc + dd);
                sj[kk] = silu(cc - dd);
            }
            bf16x2 pki, pkj;
            pki[0] = (__bf16)si[0]; pki[1] = (__bf16)si[1];
            pkj[0] = (__bf16)sj[0]; pkj[1] = (__bf16)sj[1];
            int mi = wave * 32 + 2 * le;          // x_i row; x_j row = mi+1
            int fr_i = ((mi >> 4) << 2) + q;
            int fr_j = (((mi + 1) >> 4) << 2) + q;
            int sl_i = (((mi & 15) ^ q ^ (p << 2)) & 15) + (p << 4);
            int sl_j = ((((mi + 1) & 15) ^ q ^ (p << 2)) & 15) + (p << 4);
            ((unsigned*)sH0)[fr_i * 256 + sl_i * 4 + bsub] = __builtin_bit_cast(unsigned, pki);
            ((unsigned*)sH0)[fr_j * 256 + sl_j * 4 + bsub] = __builtin_bit_cast(unsigned, pkj);
        }

        // ===== GEMM: h1_pre = H0 @ W1^T (wave-local rows, no barrier) =====
        f32x4 acc[2][8];
#pragma unroll
        for (int t = 0; t < 2; t++)
#pragma unroll
            for (int nt = 0; nt < 8; nt++)
                acc[t][nt] = (f32x4){0.f, 0.f, 0.f, 0.f};

#pragma unroll
        for (int ks = 0; ks < 4; ks++) {
            int sl_rd = (((lane & 15) ^ ks ^ (q << 2)) & 15) + 16 * q;
            bf16x8 a0 = *(const bf16x8*)(&sH0[((2 * wave + 0) * 4 + ks) * 512 + sl_rd * 8]);
            bf16x8 a1 = *(const bf16x8*)(&sH0[((2 * wave + 1) * 4 + ks) * 512 + sl_rd * 8]);
#pragma unroll
            for (int nt = 0; nt < 8; nt++) {
                bf16x8 bb = *(const bf16x8*)(&sW1[(nt * 4 + ks) * 512 + lane * 8]);
                acc[0][nt] = __builtin_amdgcn_mfma_f32_16x16x32_bf16(a0, bb, acc[0][nt], 0, 0, 0);
                acc[1][nt] = __builtin_amdgcn_mfma_f32_16x16x32_bf16(a1, bb, acc[1][nt], 0, 0, 0);
            }
        }

        // ===== epilogue: silu(h1+b1) . W2 -> +b2 -> packed f64 scatter-add =====
        float rs[2][4] = {{0.f, 0.f, 0.f, 0.f}, {0.f, 0.f, 0.f, 0.f}};
#pragma unroll
        for (int t = 0; t < 2; t++)
#pragma unroll
            for (int nt = 0; nt < 8; nt++)
#pragma unroll
                for (int r = 0; r < 4; r++) {
                    float x = acc[t][nt][r] + b1v[nt];
                    rs[t][r] = fmaf(silu(x), w2v[nt], rs[t][r]);
                }
#pragma unroll
        for (int t = 0; t < 2; t++)
#pragma unroll
            for (int r = 0; r < 4; r++) {
                float s = rs[t][r];
                s += __shfl_xor(s, 1, 64);
                s += __shfl_xor(s, 2, 64);
                s += __shfl_xor(s, 4, 64);
                s += __shfl_xor(s, 8, 64);
                int el  = t * 8 + q * 2 + (r >> 1);        // edge within wave's 16
                int src = el * 4 + (r & 1);                // comp0 lane holds i, comp1 holds j
                int node = __shfl(idx_cur, src, 64);
                int e = ebase + el;
                if (c == 0 && e < E) {
                    double contrib = (double)(s + b2f) + CNT_UNIT;
                    if (r & 1) atomicAdd(&acc_j[node], contrib);
                    else       atomicAdd(&acc_i[node], contrib);
                }
            }
        // wave-local LDS WAR across chunks is safe: one wave's DS ops are in-order.
    }
}

__global__ void finalize_kernel(const double* __restrict__ acc_i,
                                const double* __restrict__ acc_j,
                                float* __restrict__ out, int N)
{
    int n = blockIdx.x * 256 + threadIdx.x;
    if (n < N) {
        double ti = acc_i[n], tj = acc_j[n];
        double ci = rint(ti * (1.0 / CNT_UNIT));
        double cj = rint(tj * (1.0 / CNT_UNIT));
        double si = ti - ci * CNT_UNIT;
        double sj = tj - cj * CNT_UNIT;
        out[n] = (float)(si / fmax(ci, 1.0) + sj / fmax(cj, 1.0));
    }
}

extern "C" void kernel_launch(void* const* d_in, const int* in_sizes, int n_in,
                              void* d_out, int out_size, void* d_ws, size_t ws_size,
                              hipStream_t stream) {
    const float* v   = (const float*)d_in[0];
    const float* rij = (const float*)d_in[1];
    const float* W0  = (const float*)d_in[2];
    const float* b0  = (const float*)d_in[3];
    const float* W1  = (const float*)d_in[4];
    const float* b1  = (const float*)d_in[5];
    const float* W2  = (const float*)d_in[6];
    const float* b2  = (const float*)d_in[7];
    const int* eidx  = (const int*)d_in[8];

    const int E = in_sizes[1] / 3;
    const int N = out_size;

    double* acc_i = (double*)d_ws;
    double* acc_j = acc_i + N;

    hipMemsetAsync(d_ws, 0, (size_t)2 * N * sizeof(double), stream);

    int nchunks = (E + 63) / 64;
    int grid = nchunks < 512 ? nchunks : 512;
    mlp_kernel<<<grid, 256, 0, stream>>>(v, rij, W0, b0, W1, b1, W2, b2, eidx,
                                         acc_i, acc_j, E, nchunks);
    finalize_kernel<<<(N + 255) / 256, 256, 0, stream>>>(acc_i, acc_j,
                                                         (float*)d_out, N);
}